// Round 6
// baseline (177.073 us; speedup 1.0000x reference)
//
#include <hip/hip_runtime.h>
#include <math.h>

#define D      16384
#define D4     4096    // D/4
#define S      2048
#define NF     40
#define NFP    48      // padded flow count for MFMA N (3 x 16)
#define ROWS   8
#define TPB    1024
#define CH4    256
#define CHUNK  1024
#define NCHUNK 16

// ---- d_ws float offsets (fast path) ----
#define WW_OFF     0                        // WW[k][j] = w_j . w_k   (1600)
#define UW_OFF     1600                     // UW[k][j] = u_j . w_k   (1600)
#define COEF_OFF   3200                     // coef[j]                (40)
#define AT_OFF     4096                     // aT[NF][S] fp32         (81920)
#define WB_OFF     (AT_OFF + NF * S)        // Wb bf16 [NFP][D] as u32 (NFP*D/2 u32)
#define UH_OFF     (WB_OFF + (NFP * D) / 2) // uhat fp32 [NF][D]
#define WS_NEED    (UH_OFF + NF * D)        // total floats ~1.13M (4.6 MB)
#define OLD_UH_OFF 8192                     // fallback kernel's (dead) PRE pointer

typedef __attribute__((ext_vector_type(8))) __bf16 bf16x8;
typedef __attribute__((ext_vector_type(4))) float  f32x4;
union FragU { unsigned u[4]; bf16x8 b; };

__device__ __forceinline__ float dot4(float4 a, float4 b) {
    return fmaf(a.x, b.x, fmaf(a.y, b.y, fmaf(a.z, b.z, a.w * b.w)));
}
__device__ __forceinline__ void fma4(float4& o, float a, float4 u) {
    o.x = fmaf(a, u.x, o.x); o.y = fmaf(a, u.y, o.y);
    o.z = fmaf(a, u.z, o.z); o.w = fmaf(a, u.w, o.w);
}
// fp32 -> bf16 (RNE) pair pack: returns (lo | hi<<16)
__device__ __forceinline__ unsigned bpack(float lo, float hi) {
    unsigned a = __float_as_uint(lo);
    unsigned b = __float_as_uint(hi);
    a += 0x7fffu + ((a >> 16) & 1u);
    b += 0x7fffu + ((b >> 16) & 1u);
    return (a >> 16) | (b & 0xffff0000u);
}

// ---------------------------------------------------------------------------
// P1: block (k, h): WW[k][j], UW[k][j] for j in [5h,5h+5), own coef_k.
// grid 320, TPB 512.  (proven in R3/R5; doUhat always 0 now)
// ---------------------------------------------------------------------------
__global__ __launch_bounds__(512) void pair_uhat_kernel(const float* __restrict__ Wg,
                                                        const float* __restrict__ Ug,
                                                        float* __restrict__ tbl,
                                                        int doUhat) {
    const int k = blockIdx.x >> 3;
    const int h = blockIdx.x & 7;
    const int j0 = h * 5;
    const int t = threadIdx.x;
    const int wave = t >> 6, lane = t & 63;

    const float4* W4 = (const float4*)Wg;
    const float4* U4 = (const float4*)Ug;

    float ww[5], wu[5], wkk = 0.f, wku = 0.f;
    #pragma unroll
    for (int j = 0; j < 5; ++j) { ww[j] = 0.f; wu[j] = 0.f; }

    for (int i = 0; i < 8; ++i) {
        const int pos = i * 512 + t;
        float4 wk = W4[(size_t)k * D4 + pos];
        float4 uk = U4[(size_t)k * D4 + pos];
        wkk += dot4(wk, wk);
        wku += dot4(wk, uk);
        #pragma unroll
        for (int j = 0; j < 5; ++j) {
            float4 wj = W4[(size_t)(j0 + j) * D4 + pos];
            float4 uj = U4[(size_t)(j0 + j) * D4 + pos];
            ww[j] += dot4(wk, wj);
            wu[j] += dot4(wk, uj);
        }
    }

    float v[12];
    #pragma unroll
    for (int j = 0; j < 5; ++j) { v[j] = ww[j]; v[5 + j] = wu[j]; }
    v[10] = wkk; v[11] = wku;
    #pragma unroll
    for (int e = 0; e < 12; ++e) {
        #pragma unroll
        for (int off = 32; off >= 1; off >>= 1) v[e] += __shfl_xor(v[e], off);
    }

    __shared__ float red[8][12];
    __shared__ float fin[12];
    if (lane == 0) {
        #pragma unroll
        for (int e = 0; e < 12; ++e) red[wave][e] = v[e];
    }
    __syncthreads();
    if (t < 12) {
        float s = 0.f;
        #pragma unroll
        for (int w = 0; w < 8; ++w) s += red[w][t];
        fin[t] = s;
        if (t < 5)       tbl[WW_OFF + k * NF + j0 + t] = s;
        else if (t < 10) tbl[UW_OFF + k * NF + j0 + (t - 5)] = s;
    }
    __syncthreads();
    if (t == 0 && h == 0) {
        float wwd = fin[10], wud = fin[11];
        float sp = (wud > 0.f) ? (wud + log1pf(expf(-wud))) : log1pf(expf(wud));
        tbl[COEF_OFF + k] = ((-1.f + sp) - wud) / wwd;
    }
    (void)doUhat;
}

// ---------------------------------------------------------------------------
// P2: per flow row k (grid NFP=48, TPB 256):
//   Wb[k][:] = bf16(W[k][:])   (rows 40..47 -> zeros)
//   UH[k][:] = U[k][:] + coef_k * W[k][:]   (fp32, k<40 only)
// ---------------------------------------------------------------------------
__global__ __launch_bounds__(256) void conv_kernel(const float* __restrict__ Wg,
                                                   const float* __restrict__ Ug,
                                                   float* __restrict__ tbl) {
    const int k = blockIdx.x;
    unsigned* Wb = (unsigned*)(tbl + WB_OFF);
    if (k >= NF) {
        for (int i = threadIdx.x; i < D / 2; i += 256)
            Wb[(size_t)k * (D / 2) + i] = 0u;
        return;
    }
    const float cf = tbl[COEF_OFF + k];
    const float4* W4 = (const float4*)Wg + (size_t)k * D4;
    const float4* U4 = (const float4*)Ug + (size_t)k * D4;
    float4* UH4 = (float4*)(tbl + UH_OFF) + (size_t)k * D4;
    uint2* Wb2 = (uint2*)(Wb + (size_t)k * (D / 2));
    for (int i = threadIdx.x; i < D4; i += 256) {
        float4 w = W4[i], u = U4[i];
        float4 r;
        r.x = fmaf(cf, w.x, u.x); r.y = fmaf(cf, w.y, u.y);
        r.z = fmaf(cf, w.z, u.z); r.w = fmaf(cf, w.w, u.w);
        UH4[i] = r;
        uint2 p; p.x = bpack(w.x, w.y); p.y = bpack(w.z, w.w);
        Wb2[i] = p;
    }
}

// ---------------------------------------------------------------------------
// AB: per block 16 rows (grid 128, TPB 512 = 8 waves, K-split 8 x 2048):
//   MFMA c0 = X . W^T (bf16 inputs, fp32 acc), LDS-reduce K-splits,
//   then the proven 40-step recurrence -> aT[j][row] fp32.
// A-frag: row = lane&15, k = kb + (lane>>4)*8 + e  (X fp32 -> bf16 inline)
// B-frag: col = lane&15 (flow idx), same k -> Wb[col][k..k+8) 16B contiguous
// D-frag: row = (lane>>4)*4 + q, col = lane&15 (HW-verified map)
// ---------------------------------------------------------------------------
__global__ __launch_bounds__(512) void gemm_rec_kernel(const float* __restrict__ Xg,
                                                       const float* __restrict__ Bg,
                                                       float* __restrict__ tbl) {
    const int t = threadIdx.x, w = t >> 6, l = t & 63;
    const int rowBase = blockIdx.x * 16;

    __shared__ float red[8][16][NFP + 1];
    __shared__ float gts[NF][NF + 1];
    __shared__ float c0s[16][NF + 1];
    __shared__ float bsS[NF];

    for (int e = t; e < NF * NF; e += 512) {
        const int jj = e % NF;
        gts[e / NF][jj] = tbl[UW_OFF + e] + tbl[COEF_OFF + jj] * tbl[WW_OFF + e];
    }
    if (t < NF) bsS[t] = Bg[t];

    const int r = l & 15, kg = l >> 4;
    const unsigned* WbU = (const unsigned*)(tbl + WB_OFF);
    f32x4 acc0 = {0.f, 0.f, 0.f, 0.f};
    f32x4 acc1 = acc0, acc2 = acc0;
    const float*    xrow = Xg + (size_t)(rowBase + r) * D + kg * 8;
    const unsigned* b0p = WbU + (size_t)(r)      * (D / 2) + kg * 4;
    const unsigned* b1p = WbU + (size_t)(16 + r) * (D / 2) + kg * 4;
    const unsigned* b2p = WbU + (size_t)(32 + r) * (D / 2) + kg * 4;

    #pragma unroll 2
    for (int kk = 0; kk < 2048; kk += 32) {
        const int kb = w * 2048 + kk;
        float4 xa = *(const float4*)(xrow + kb);
        float4 xb = *(const float4*)(xrow + kb + 4);
        FragU af;
        af.u[0] = bpack(xa.x, xa.y); af.u[1] = bpack(xa.z, xa.w);
        af.u[2] = bpack(xb.x, xb.y); af.u[3] = bpack(xb.z, xb.w);
        const int ku = kb >> 1;
        bf16x8 b0 = *(const bf16x8*)(b0p + ku);
        bf16x8 b1 = *(const bf16x8*)(b1p + ku);
        bf16x8 b2 = *(const bf16x8*)(b2p + ku);
        acc0 = __builtin_amdgcn_mfma_f32_16x16x32_bf16(af.b, b0, acc0, 0, 0, 0);
        acc1 = __builtin_amdgcn_mfma_f32_16x16x32_bf16(af.b, b1, acc1, 0, 0, 0);
        acc2 = __builtin_amdgcn_mfma_f32_16x16x32_bf16(af.b, b2, acc2, 0, 0, 0);
    }

    #pragma unroll
    for (int q = 0; q < 4; ++q) {
        red[w][kg * 4 + q][r]      = acc0[q];
        red[w][kg * 4 + q][16 + r] = acc1[q];
        red[w][kg * 4 + q][32 + r] = acc2[q];
    }
    __syncthreads();

    // sum K-split partials (+bias) for this wave's 2 rows
    #pragma unroll
    for (int rr = 0; rr < 2; ++rr) {
        const int row = w * 2 + rr;
        if (l < NF) {
            float s = 0.f;
            #pragma unroll
            for (int ww = 0; ww < 8; ++ww) s += red[ww][row][l];
            c0s[row][l] = s + bsS[l];
        }
    }
    __syncthreads();

    // recurrence (R2-proven pattern), wave w -> rows 2w, 2w+1
    float* aT = tbl + AT_OFF;
    #pragma unroll 1
    for (int rr = 0; rr < 2; ++rr) {
        const int row = w * 2 + rr;
        const int j = l;
        float aj = 0.f;
        for (int k = 0; k < NF; ++k) {
            float gv = (j < k) ? gts[k][j] : 0.f;
            float tv = aj * gv;
            #pragma unroll
            for (int off = 32; off >= 1; off >>= 1) tv += __shfl_xor(tv, off);
            float ak = tanhf(c0s[row][k] + tv);
            if (j == k) aj = ak;
        }
        if (j < NF) aT[(size_t)j * S + rowBase + row] = aj;
    }
}

// ---------------------------------------------------------------------------
// C: out[r] = x0[r] + sum_k a[r][k] * uhat_k.  grid 2048 (256 row-blocks x 8
// col-eighths), TPB 256, zero LDS -> 32 waves/CU. a-values read as uniform
// scalars (s_load broadcast), uh streamed f4 from L2-resident UH.
// ---------------------------------------------------------------------------
__global__ __launch_bounds__(256) void apply_kernel(const float* __restrict__ Xg,
                                                    const float* __restrict__ tbl,
                                                    float* __restrict__ Og) {
    const int bid = blockIdx.x;
    const int rblk = bid >> 3, cq = bid & 7;
    const int t = threadIdx.x;
    const int r0 = rblk * 8;

    const float4* X4  = (const float4*)Xg;
    const float4* UH4 = (const float4*)(tbl + UH_OFF);
    const float*  aT  = tbl + AT_OFF;
    float4* O4 = (float4*)Og;

    #pragma unroll 1
    for (int p = 0; p < 2; ++p) {
        const int col = cq * 512 + p * 256 + t;
        float4 o[8];
        #pragma unroll
        for (int r = 0; r < 8; ++r)
            o[r] = X4[(size_t)(r0 + r) * D4 + col];

        #pragma unroll 2
        for (int k = 0; k < NF; ++k) {
            float4 uh = UH4[(size_t)k * D4 + col];
            const float* ap = aT + (size_t)k * S + r0;   // uniform -> s_load
            fma4(o[0], ap[0], uh); fma4(o[1], ap[1], uh);
            fma4(o[2], ap[2], uh); fma4(o[3], ap[3], uh);
            fma4(o[4], ap[4], uh); fma4(o[5], ap[5], uh);
            fma4(o[6], ap[6], uh); fma4(o[7], ap[7], uh);
        }
        #pragma unroll
        for (int r = 0; r < 8; ++r)
            O4[(size_t)(r0 + r) * D4 + col] = o[r];
    }
}

// ---------------------------------------------------------------------------
// Fallback (ws too small for the MFMA path): R5's proven scalar kernel,
// non-PRE flavor (uhat recomputed on the fly from W,U,coef).
// ---------------------------------------------------------------------------
__global__ __launch_bounds__(TPB) void flow_main_fb(const float* __restrict__ Xg,
                                                    const float* __restrict__ Wg,
                                                    const float* __restrict__ Ug,
                                                    const float* __restrict__ Bg,
                                                    const float* __restrict__ tbl,
                                                    float* __restrict__ Og) {
    const int t = threadIdx.x;
    const int wave = t >> 6, lane = t & 63;
    const int rowBase = blockIdx.x * ROWS;

    __shared__ __align__(16) float xs[2][ROWS][CHUNK];
    __shared__ __align__(16) float gts[NF][NF + 1];
    __shared__ __align__(16) float c0p[NF][ROWS];
    __shared__ __align__(16) float aTs[NF][ROWS];
    __shared__ float bsS[NF];
    __shared__ float coefS[NF];

    const float4* X4 = (const float4*)Xg;
    const float4* W4 = (const float4*)Wg;
    const float4* U4 = (const float4*)Ug;

    for (int e = t; e < NF * NF; e += TPB) {
        const int jj = e % NF;
        gts[e / NF][jj] = tbl[UW_OFF + e] + tbl[COEF_OFF + jj] * tbl[WW_OFF + e];
    }
    if (t < NF) { bsS[t] = Bg[t]; coefS[t] = tbl[COEF_OFF + t]; }

    const int srow = (t >> 8) * 2;
    const int sc4  = t & 255;

    float4 p0 = X4[(size_t)(rowBase + srow)     * D4 + sc4];
    float4 p1 = X4[(size_t)(rowBase + srow + 1) * D4 + sc4];
    *(float4*)&xs[0][srow][sc4 * 4]     = p0;
    *(float4*)&xs[0][srow + 1][sc4 * 4] = p1;
    __syncthreads();

    const int kt = wave & 7, rt = wave >> 3;
    const int k0 = kt * 5, r0 = rt * 4;

    float acc[4][5];
    #pragma unroll
    for (int r = 0; r < 4; ++r)
        #pragma unroll
        for (int kk = 0; kk < 5; ++kk) acc[r][kk] = 0.f;

    int b = 0;
    for (int c = 0; c < NCHUNK; ++c) {
        if (c + 1 < NCHUNK) {
            p0 = X4[(size_t)(rowBase + srow)     * D4 + (c + 1) * CH4 + sc4];
            p1 = X4[(size_t)(rowBase + srow + 1) * D4 + (c + 1) * CH4 + sc4];
        }
        #pragma unroll 1
        for (int s = 0; s < 4; ++s) {
            const int col4 = c * CH4 + s * 64 + lane;
            float4 wv[5];
            #pragma unroll
            for (int kk = 0; kk < 5; ++kk)
                wv[kk] = W4[(size_t)(k0 + kk) * D4 + col4];
            const int lc = (s * 64 + lane) * 4;
            #pragma unroll
            for (int r = 0; r < 4; ++r) {
                float4 xv = *(const float4*)&xs[b][r0 + r][lc];
                #pragma unroll
                for (int kk = 0; kk < 5; ++kk)
                    acc[r][kk] = fmaf(xv.x, wv[kk].x,
                                 fmaf(xv.y, wv[kk].y,
                                 fmaf(xv.z, wv[kk].z,
                                 fmaf(xv.w, wv[kk].w, acc[r][kk]))));
            }
        }
        if (c + 1 < NCHUNK) {
            *(float4*)&xs[b ^ 1][srow][sc4 * 4]     = p0;
            *(float4*)&xs[b ^ 1][srow + 1][sc4 * 4] = p1;
        }
        __syncthreads();
        b ^= 1;
    }

    #pragma unroll
    for (int r = 0; r < 4; ++r)
        #pragma unroll
        for (int kk = 0; kk < 5; ++kk) {
            float v = acc[r][kk];
            #pragma unroll
            for (int off = 32; off >= 1; off >>= 1) v += __shfl_xor(v, off);
            acc[r][kk] = v;
        }
    if (lane == 0) {
        #pragma unroll
        for (int kk = 0; kk < 5; ++kk)
            #pragma unroll
            for (int r = 0; r < 4; ++r)
                c0p[k0 + kk][r0 + r] = acc[r][kk];
    }
    __syncthreads();

    float4 o[ROWS];
    {
        const int col = wave * 64 + lane;
        #pragma unroll
        for (int r = 0; r < ROWS; ++r)
            o[r] = X4[(size_t)(rowBase + r) * D4 + col];
    }

    if (wave < ROWS) {
        const int r = wave, j = lane;
        float aj = 0.f;
        for (int k = 0; k < NF; ++k) {
            float gv = (j < k) ? gts[k][j] : 0.f;
            float tv = aj * gv;
            #pragma unroll
            for (int off = 32; off >= 1; off >>= 1) tv += __shfl_xor(tv, off);
            float sum = c0p[k][r] + bsS[k] + tv;
            float ak = tanhf(sum);
            if (j == k) aj = ak;
        }
        if (j < NF) aTs[j][r] = aj;
    }
    __syncthreads();

    float4* O4 = (float4*)Og;
    #pragma unroll 1
    for (int p = 0; p < 4; ++p) {
        const int col = p * 1024 + wave * 64 + lane;
        if (p > 0) {
            #pragma unroll
            for (int r = 0; r < ROWS; ++r)
                o[r] = X4[(size_t)(rowBase + r) * D4 + col];
        }
        #pragma unroll 2
        for (int k = 0; k < NF; ++k) {
            float4 uu = U4[(size_t)k * D4 + col];
            float4 wv = W4[(size_t)k * D4 + col];
            const float cf = coefS[k];
            float4 uh;
            uh.x = fmaf(cf, wv.x, uu.x);
            uh.y = fmaf(cf, wv.y, uu.y);
            uh.z = fmaf(cf, wv.z, uu.z);
            uh.w = fmaf(cf, wv.w, uu.w);
            float4 alo = *(const float4*)&aTs[k][0];
            float4 ahi = *(const float4*)&aTs[k][4];
            fma4(o[0], alo.x, uh); fma4(o[1], alo.y, uh);
            fma4(o[2], alo.z, uh); fma4(o[3], alo.w, uh);
            fma4(o[4], ahi.x, uh); fma4(o[5], ahi.y, uh);
            fma4(o[6], ahi.z, uh); fma4(o[7], ahi.w, uh);
        }
        #pragma unroll
        for (int r = 0; r < ROWS; ++r)
            O4[(size_t)(rowBase + r) * D4 + col] = o[r];
    }
}

extern "C" void kernel_launch(void* const* d_in, const int* in_sizes, int n_in,
                              void* d_out, int out_size, void* d_ws, size_t ws_size,
                              hipStream_t stream) {
    const float* X  = (const float*)d_in[0];
    const float* Wg = (const float*)d_in[1];
    const float* Ug = (const float*)d_in[2];
    const float* Bg = (const float*)d_in[3];
    float* out = (float*)d_out;
    float* tbl = (float*)d_ws;

    const bool fast = ws_size >= (size_t)WS_NEED * sizeof(float);

    pair_uhat_kernel<<<NF * 8, 512, 0, stream>>>(Wg, Ug, tbl, 0);
    if (fast) {
        conv_kernel<<<NFP, 256, 0, stream>>>(Wg, Ug, tbl);
        gemm_rec_kernel<<<S / 16, 512, 0, stream>>>(X, Bg, tbl);
        apply_kernel<<<(S / 8) * 8, 256, 0, stream>>>(X, tbl, out);
    } else {
        flow_main_fb<<<S / ROWS, TPB, 0, stream>>>(X, Wg, Ug, Bg, tbl, out);
    }
}

// Round 7
// 142.875 us; speedup vs baseline: 1.2394x; 1.2394x over previous
//
#include <hip/hip_runtime.h>
#include <math.h>

#define D      16384
#define D4     4096    // D/4
#define S      2048
#define NF     40
#define NFP    48      // padded flow count for MFMA (3 x 16)
#define ROWS   8
#define TPB    1024
#define CH4    256
#define CHUNK  1024
#define NCHUNK 16
#define KSPLIT 8       // K-splits in the MFMA GEMM

// ---- d_ws float offsets (fast path), total 4,538,368 B (== R6's, known OK) ----
#define WW_OFF     0                        // WW[k][j] = w_j . w_k   (1600)
#define UW_OFF     1600                     // UW[k][j] = u_j . w_k   (1600)
#define COEF_OFF   3200                     // coef[j]                (40)
#define AT_OFF     4096                     // aT[NF][S] fp32         (81920)
#define WB_OFF     (AT_OFF + NF * S)        // Wb bf16 [NFP][D] as u32 (NFP*D/2 slots)
#define C0P_OFF    (WB_OFF + (NFP * D) / 2) // c0 partials [S][KSPLIT][NF]
#define WS_NEED    (C0P_OFF + S * KSPLIT * NF)

typedef __attribute__((ext_vector_type(8))) __bf16 bf16x8;
typedef __attribute__((ext_vector_type(4))) float  f32x4;
union FragU { unsigned u[4]; bf16x8 b; };

__device__ __forceinline__ float dot4(float4 a, float4 b) {
    return fmaf(a.x, b.x, fmaf(a.y, b.y, fmaf(a.z, b.z, a.w * b.w)));
}
__device__ __forceinline__ void fma4(float4& o, float a, float4 u) {
    o.x = fmaf(a, u.x, o.x); o.y = fmaf(a, u.y, o.y);
    o.z = fmaf(a, u.z, o.z); o.w = fmaf(a, u.w, o.w);
}
// fp32 -> bf16 (RNE) pair pack: returns (lo | hi<<16)
__device__ __forceinline__ unsigned bpack(float lo, float hi) {
    unsigned a = __float_as_uint(lo);
    unsigned b = __float_as_uint(hi);
    a += 0x7fffu + ((a >> 16) & 1u);
    b += 0x7fffu + ((b >> 16) & 1u);
    return (a >> 16) | (b & 0xffff0000u);
}

// ---------------------------------------------------------------------------
// P1: block (k, h), grid NFP*8 = 384, TPB 512.
//   k<40: WW[k][j], UW[k][j] for j in [5h,5h+5); coef_k (h==0 writes);
//         Wb[k] bf16 slice h (reuses the i==h W load — zero extra traffic).
//   k>=40: zero-pad Wb row slice.
// ---------------------------------------------------------------------------
__global__ __launch_bounds__(512) void pair_wb_kernel(const float* __restrict__ Wg,
                                                      const float* __restrict__ Ug,
                                                      float* __restrict__ tbl) {
    const int k = blockIdx.x >> 3;
    const int h = blockIdx.x & 7;
    const int t = threadIdx.x;
    uint2* Wb2 = (uint2*)((unsigned*)(tbl + WB_OFF) + (size_t)k * (D / 2));

    if (k >= NF) {                       // zero-pad rows 40..47
        Wb2[h * 512 + t] = make_uint2(0u, 0u);
        return;
    }

    const int j0 = h * 5;
    const int wave = t >> 6, lane = t & 63;
    const float4* W4 = (const float4*)Wg;
    const float4* U4 = (const float4*)Ug;

    float ww[5], wu[5], wkk = 0.f, wku = 0.f;
    float4 wkSave;
    #pragma unroll
    for (int j = 0; j < 5; ++j) { ww[j] = 0.f; wu[j] = 0.f; }

    for (int i = 0; i < 8; ++i) {
        const int pos = i * 512 + t;
        float4 wk = W4[(size_t)k * D4 + pos];
        float4 uk = U4[(size_t)k * D4 + pos];
        if (i == h) wkSave = wk;
        wkk += dot4(wk, wk);
        wku += dot4(wk, uk);
        #pragma unroll
        for (int j = 0; j < 5; ++j) {
            float4 wj = W4[(size_t)(j0 + j) * D4 + pos];
            float4 uj = U4[(size_t)(j0 + j) * D4 + pos];
            ww[j] += dot4(wk, wj);
            wu[j] += dot4(wk, uj);
        }
    }

    // write this block's Wb slice (bf16)
    {
        uint2 p;
        p.x = bpack(wkSave.x, wkSave.y);
        p.y = bpack(wkSave.z, wkSave.w);
        Wb2[h * 512 + t] = p;
    }

    float v[12];
    #pragma unroll
    for (int j = 0; j < 5; ++j) { v[j] = ww[j]; v[5 + j] = wu[j]; }
    v[10] = wkk; v[11] = wku;
    #pragma unroll
    for (int e = 0; e < 12; ++e) {
        #pragma unroll
        for (int off = 32; off >= 1; off >>= 1) v[e] += __shfl_xor(v[e], off);
    }

    __shared__ float red[8][12];
    __shared__ float fin[12];
    if (lane == 0) {
        #pragma unroll
        for (int e = 0; e < 12; ++e) red[wave][e] = v[e];
    }
    __syncthreads();
    if (t < 12) {
        float s = 0.f;
        #pragma unroll
        for (int w = 0; w < 8; ++w) s += red[w][t];
        fin[t] = s;
        if (t < 5)       tbl[WW_OFF + k * NF + j0 + t] = s;
        else if (t < 10) tbl[UW_OFF + k * NF + j0 + (t - 5)] = s;
    }
    __syncthreads();
    if (t == 0 && h == 0) {
        float wwd = fin[10], wud = fin[11];
        float sp = (wud > 0.f) ? (wud + log1pf(expf(-wud))) : log1pf(expf(wud));
        tbl[COEF_OFF + k] = ((-1.f + sp) - wud) / wwd;
    }
}

// ---------------------------------------------------------------------------
// G: MFMA partial GEMM. grid = 128 row-tiles x KSPLIT=8 -> 1024 blocks,
// TPB 256 (4 waves). Block (rt, ks): c0 partial for rows [16rt,16rt+16)
// over K-slice [2048ks, 2048ks+2048); wave w covers 512 of it.
// Fragment maps HW-verified in R6 (passed absmax 0.031).
// ---------------------------------------------------------------------------
__global__ __launch_bounds__(256) void gemm_part_kernel(const float* __restrict__ Xg,
                                                        float* __restrict__ tbl) {
    const int t = threadIdx.x, w = t >> 6, l = t & 63;
    const int rt = blockIdx.x >> 3, ks = blockIdx.x & 7;
    const int r = l & 15, kg = l >> 4;

    __shared__ float red[4][16][NFP + 1];

    const unsigned* WbU = (const unsigned*)(tbl + WB_OFF);
    f32x4 acc0 = {0.f, 0.f, 0.f, 0.f};
    f32x4 acc1 = acc0, acc2 = acc0;

    const float*    xrow = Xg + (size_t)(rt * 16 + r) * D + kg * 8;
    const unsigned* b0p = WbU + (size_t)(r)      * (D / 2) + kg * 4;
    const unsigned* b1p = WbU + (size_t)(16 + r) * (D / 2) + kg * 4;
    const unsigned* b2p = WbU + (size_t)(32 + r) * (D / 2) + kg * 4;
    const int kbase = ks * 2048 + w * 512;

    #pragma unroll 4
    for (int kk = 0; kk < 512; kk += 32) {
        const int kb = kbase + kk;
        float4 xa = *(const float4*)(xrow + kb);
        float4 xb = *(const float4*)(xrow + kb + 4);
        FragU af;
        af.u[0] = bpack(xa.x, xa.y); af.u[1] = bpack(xa.z, xa.w);
        af.u[2] = bpack(xb.x, xb.y); af.u[3] = bpack(xb.z, xb.w);
        const int ku = kb >> 1;
        bf16x8 b0 = *(const bf16x8*)(b0p + ku);
        bf16x8 b1 = *(const bf16x8*)(b1p + ku);
        bf16x8 b2 = *(const bf16x8*)(b2p + ku);
        acc0 = __builtin_amdgcn_mfma_f32_16x16x32_bf16(af.b, b0, acc0, 0, 0, 0);
        acc1 = __builtin_amdgcn_mfma_f32_16x16x32_bf16(af.b, b1, acc1, 0, 0, 0);
        acc2 = __builtin_amdgcn_mfma_f32_16x16x32_bf16(af.b, b2, acc2, 0, 0, 0);
    }

    #pragma unroll
    for (int q = 0; q < 4; ++q) {
        red[w][kg * 4 + q][r]      = acc0[q];
        red[w][kg * 4 + q][16 + r] = acc1[q];
        red[w][kg * 4 + q][32 + r] = acc2[q];
    }
    __syncthreads();

    float* c0p = tbl + C0P_OFF;
    for (int e = t; e < 16 * NF; e += 256) {
        const int row = e / NF, fl = e - row * NF;
        float s = red[0][row][fl] + red[1][row][fl] +
                  red[2][row][fl] + red[3][row][fl];
        c0p[((size_t)(rt * 16 + row) * KSPLIT + ks) * NF + fl] = s;
    }
}

// ---------------------------------------------------------------------------
// R: reduce K-split partials + 40-step recurrence -> aT[j][row].
// grid 128, TPB 1024 (16 waves, one wave per row of the 16-row tile).
// ---------------------------------------------------------------------------
__global__ __launch_bounds__(1024) void reduce_rec_kernel(const float* __restrict__ Bg,
                                                          float* __restrict__ tbl) {
    const int t = threadIdx.x;
    const int wave = t >> 6, lane = t & 63;

    __shared__ float gts[NF][NF + 1];
    __shared__ float bsS[NF];
    for (int e = t; e < NF * NF; e += 1024) {
        const int jj = e % NF;
        gts[e / NF][jj] = tbl[UW_OFF + e] + tbl[COEF_OFF + jj] * tbl[WW_OFF + e];
    }
    if (t < NF) bsS[t] = Bg[t];
    __syncthreads();

    const int g = blockIdx.x * 16 + wave;
    const float* cp = tbl + C0P_OFF + (size_t)g * (KSPLIT * NF);

    float c0 = 0.f;
    if (lane < NF) {
        #pragma unroll
        for (int s = 0; s < KSPLIT; ++s) c0 += cp[s * NF + lane];
        c0 += bsS[lane];
    }

    float aj = 0.f;
    for (int k = 0; k < NF; ++k) {
        float gv = (lane < k) ? gts[k][lane] : 0.f;
        float tv = aj * gv;
        #pragma unroll
        for (int off = 32; off >= 1; off >>= 1) tv += __shfl_xor(tv, off);
        float ck = __shfl(c0, k);
        float ak = tanhf(ck + tv);
        if (lane == k) aj = ak;
    }
    if (lane < NF) tbl[AT_OFF + (size_t)lane * S + g] = aj;
}

// ---------------------------------------------------------------------------
// C: out[r] = x0[r] + sum_k a[r][k] * (u_k + coef_k*w_k).  grid 2048
// (256 row-blocks x 8 col-eighths), TPB 256, zero LDS -> high occupancy.
// a-values and coef are wave-uniform (s_load broadcast).
// ---------------------------------------------------------------------------
__global__ __launch_bounds__(256) void apply_kernel(const float* __restrict__ Xg,
                                                    const float* __restrict__ Wg,
                                                    const float* __restrict__ Ug,
                                                    const float* __restrict__ tbl,
                                                    float* __restrict__ Og) {
    const int bid = blockIdx.x;
    const int rblk = bid >> 3, cq = bid & 7;
    const int t = threadIdx.x;
    const int r0 = rblk * 8;

    const float4* X4 = (const float4*)Xg;
    const float4* W4 = (const float4*)Wg;
    const float4* U4 = (const float4*)Ug;
    const float*  aT = tbl + AT_OFF;
    float4* O4 = (float4*)Og;

    #pragma unroll 1
    for (int p = 0; p < 2; ++p) {
        const int col = cq * 512 + p * 256 + t;
        float4 o[8];
        #pragma unroll
        for (int r = 0; r < 8; ++r)
            o[r] = X4[(size_t)(r0 + r) * D4 + col];

        #pragma unroll 2
        for (int k = 0; k < NF; ++k) {
            float4 wv = W4[(size_t)k * D4 + col];
            float4 uu = U4[(size_t)k * D4 + col];
            const float cf = tbl[COEF_OFF + k];
            float4 uh;
            uh.x = fmaf(cf, wv.x, uu.x);
            uh.y = fmaf(cf, wv.y, uu.y);
            uh.z = fmaf(cf, wv.z, uu.z);
            uh.w = fmaf(cf, wv.w, uu.w);
            const float* ap = aT + (size_t)k * S + r0;   // uniform -> s_load
            fma4(o[0], ap[0], uh); fma4(o[1], ap[1], uh);
            fma4(o[2], ap[2], uh); fma4(o[3], ap[3], uh);
            fma4(o[4], ap[4], uh); fma4(o[5], ap[5], uh);
            fma4(o[6], ap[6], uh); fma4(o[7], ap[7], uh);
        }
        #pragma unroll
        for (int r = 0; r < 8; ++r)
            O4[(size_t)(r0 + r) * D4 + col] = o[r];
    }
}

// ---------------------------------------------------------------------------
// Fallback (ws too small): R5's proven scalar kernel (190 us, passes).
// ---------------------------------------------------------------------------
__global__ __launch_bounds__(TPB) void flow_main_fb(const float* __restrict__ Xg,
                                                    const float* __restrict__ Wg,
                                                    const float* __restrict__ Ug,
                                                    const float* __restrict__ Bg,
                                                    const float* __restrict__ tbl,
                                                    float* __restrict__ Og) {
    const int t = threadIdx.x;
    const int wave = t >> 6, lane = t & 63;
    const int rowBase = blockIdx.x * ROWS;

    __shared__ __align__(16) float xs[2][ROWS][CHUNK];
    __shared__ __align__(16) float gts[NF][NF + 1];
    __shared__ __align__(16) float c0p[NF][ROWS];
    __shared__ __align__(16) float aTs[NF][ROWS];
    __shared__ float bsS[NF];
    __shared__ float coefS[NF];

    const float4* X4 = (const float4*)Xg;
    const float4* W4 = (const float4*)Wg;
    const float4* U4 = (const float4*)Ug;

    for (int e = t; e < NF * NF; e += TPB) {
        const int jj = e % NF;
        gts[e / NF][jj] = tbl[UW_OFF + e] + tbl[COEF_OFF + jj] * tbl[WW_OFF + e];
    }
    if (t < NF) { bsS[t] = Bg[t]; coefS[t] = tbl[COEF_OFF + t]; }

    const int srow = (t >> 8) * 2;
    const int sc4  = t & 255;

    float4 p0 = X4[(size_t)(rowBase + srow)     * D4 + sc4];
    float4 p1 = X4[(size_t)(rowBase + srow + 1) * D4 + sc4];
    *(float4*)&xs[0][srow][sc4 * 4]     = p0;
    *(float4*)&xs[0][srow + 1][sc4 * 4] = p1;
    __syncthreads();

    const int kt = wave & 7, rt = wave >> 3;
    const int k0 = kt * 5, r0 = rt * 4;

    float acc[4][5];
    #pragma unroll
    for (int r = 0; r < 4; ++r)
        #pragma unroll
        for (int kk = 0; kk < 5; ++kk) acc[r][kk] = 0.f;

    int b = 0;
    for (int c = 0; c < NCHUNK; ++c) {
        if (c + 1 < NCHUNK) {
            p0 = X4[(size_t)(rowBase + srow)     * D4 + (c + 1) * CH4 + sc4];
            p1 = X4[(size_t)(rowBase + srow + 1) * D4 + (c + 1) * CH4 + sc4];
        }
        #pragma unroll 1
        for (int s = 0; s < 4; ++s) {
            const int col4 = c * CH4 + s * 64 + lane;
            float4 wv[5];
            #pragma unroll
            for (int kk = 0; kk < 5; ++kk)
                wv[kk] = W4[(size_t)(k0 + kk) * D4 + col4];
            const int lc = (s * 64 + lane) * 4;
            #pragma unroll
            for (int r = 0; r < 4; ++r) {
                float4 xv = *(const float4*)&xs[b][r0 + r][lc];
                #pragma unroll
                for (int kk = 0; kk < 5; ++kk)
                    acc[r][kk] = fmaf(xv.x, wv[kk].x,
                                 fmaf(xv.y, wv[kk].y,
                                 fmaf(xv.z, wv[kk].z,
                                 fmaf(xv.w, wv[kk].w, acc[r][kk]))));
            }
        }
        if (c + 1 < NCHUNK) {
            *(float4*)&xs[b ^ 1][srow][sc4 * 4]     = p0;
            *(float4*)&xs[b ^ 1][srow + 1][sc4 * 4] = p1;
        }
        __syncthreads();
        b ^= 1;
    }

    #pragma unroll
    for (int r = 0; r < 4; ++r)
        #pragma unroll
        for (int kk = 0; kk < 5; ++kk) {
            float v = acc[r][kk];
            #pragma unroll
            for (int off = 32; off >= 1; off >>= 1) v += __shfl_xor(v, off);
            acc[r][kk] = v;
        }
    if (lane == 0) {
        #pragma unroll
        for (int kk = 0; kk < 5; ++kk)
            #pragma unroll
            for (int r = 0; r < 4; ++r)
                c0p[k0 + kk][r0 + r] = acc[r][kk];
    }
    __syncthreads();

    float4 o[ROWS];
    {
        const int col = wave * 64 + lane;
        #pragma unroll
        for (int r = 0; r < ROWS; ++r)
            o[r] = X4[(size_t)(rowBase + r) * D4 + col];
    }

    if (wave < ROWS) {
        const int r = wave, j = lane;
        float aj = 0.f;
        for (int k = 0; k < NF; ++k) {
            float gv = (j < k) ? gts[k][j] : 0.f;
            float tv = aj * gv;
            #pragma unroll
            for (int off = 32; off >= 1; off >>= 1) tv += __shfl_xor(tv, off);
            float sum = c0p[k][r] + bsS[k] + tv;
            float ak = tanhf(sum);
            if (j == k) aj = ak;
        }
        if (j < NF) aTs[j][r] = aj;
    }
    __syncthreads();

    float4* O4 = (float4*)Og;
    #pragma unroll 1
    for (int p = 0; p < 4; ++p) {
        const int col = p * 1024 + wave * 64 + lane;
        if (p > 0) {
            #pragma unroll
            for (int r = 0; r < ROWS; ++r)
                o[r] = X4[(size_t)(rowBase + r) * D4 + col];
        }
        #pragma unroll 2
        for (int k = 0; k < NF; ++k) {
            float4 uu = U4[(size_t)k * D4 + col];
            float4 wv = W4[(size_t)k * D4 + col];
            const float cf = coefS[k];
            float4 uh;
            uh.x = fmaf(cf, wv.x, uu.x);
            uh.y = fmaf(cf, wv.y, uu.y);
            uh.z = fmaf(cf, wv.z, uu.z);
            uh.w = fmaf(cf, wv.w, uu.w);
            float4 alo = *(const float4*)&aTs[k][0];
            float4 ahi = *(const float4*)&aTs[k][4];
            fma4(o[0], alo.x, uh); fma4(o[1], alo.y, uh);
            fma4(o[2], alo.z, uh); fma4(o[3], alo.w, uh);
            fma4(o[4], ahi.x, uh); fma4(o[5], ahi.y, uh);
            fma4(o[6], ahi.z, uh); fma4(o[7], ahi.w, uh);
        }
        #pragma unroll
        for (int r = 0; r < ROWS; ++r)
            O4[(size_t)(rowBase + r) * D4 + col] = o[r];
    }
}

extern "C" void kernel_launch(void* const* d_in, const int* in_sizes, int n_in,
                              void* d_out, int out_size, void* d_ws, size_t ws_size,
                              hipStream_t stream) {
    const float* X  = (const float*)d_in[0];
    const float* Wg = (const float*)d_in[1];
    const float* Ug = (const float*)d_in[2];
    const float* Bg = (const float*)d_in[3];
    float* out = (float*)d_out;
    float* tbl = (float*)d_ws;

    const bool fast = ws_size >= (size_t)WS_NEED * sizeof(float);

    if (fast) {
        pair_wb_kernel<<<NFP * 8, 512, 0, stream>>>(Wg, Ug, tbl);
        gemm_part_kernel<<<(S / 16) * KSPLIT, 256, 0, stream>>>(X, tbl);
        reduce_rec_kernel<<<S / 16, 1024, 0, stream>>>(Bg, tbl);
        apply_kernel<<<(S / 8) * 8, 256, 0, stream>>>(X, Wg, Ug, tbl, out);
    } else {
        pair_wb_kernel<<<NF * 8, 512, 0, stream>>>(Wg, Ug, tbl);  // k<40 only
        flow_main_fb<<<S / ROWS, TPB, 0, stream>>>(X, Wg, Ug, Bg, tbl, out);
    }
}

// Round 9
// 129.813 us; speedup vs baseline: 1.3641x; 1.1006x over previous
//
#include <hip/hip_runtime.h>
#include <math.h>

#define D      16384
#define D4     4096    // D/4
#define S      2048
#define NF     40
#define NFP    48      // padded flow count for MFMA (3 x 16)
#define ROWS   8
#define TPB    1024
#define CH4    256
#define CHUNK  1024
#define NCHUNK 16
#define KSPLIT 8       // K-splits in the MFMA GEMM

// ---- d_ws float offsets (fast path), total 4,538,368 B (== R6/R7, known OK) ----
#define WW_OFF     0                        // WW[k][j] = w_j . w_k   (1600)
#define UW_OFF     1600                     // UW[k][j] = u_j . w_k   (1600)
#define COEF_OFF   3200                     // coef[j]                (40)
#define AT_OFF     4096                     // aT[S][NF] fp32         (81920)
#define WB_OFF     (AT_OFF + NF * S)        // Wb bf16 [NFP][D] as u32 (NFP*D/2 slots)
#define C0P_OFF    (WB_OFF + (NFP * D) / 2) // c0 partials [S][KSPLIT][NF]  (655360)
#define UH_OFF     C0P_OFF                  // uhat fp32 [NF][D] ALIASES c0p (dead after
                                            // reduce_rec; stream order = graph dep).
#define WS_NEED    (C0P_OFF + S * KSPLIT * NF)

typedef __attribute__((ext_vector_type(8))) __bf16 bf16x8;
typedef __attribute__((ext_vector_type(4))) float  f32x4;
union FragU { unsigned u[4]; bf16x8 b; };

__device__ __forceinline__ float dot4(float4 a, float4 b) {
    return fmaf(a.x, b.x, fmaf(a.y, b.y, fmaf(a.z, b.z, a.w * b.w)));
}
__device__ __forceinline__ void fma4(float4& o, float a, float4 u) {
    o.x = fmaf(a, u.x, o.x); o.y = fmaf(a, u.y, o.y);
    o.z = fmaf(a, u.z, o.z); o.w = fmaf(a, u.w, o.w);
}
// fp32 -> bf16 (RNE) pair pack: returns (lo | hi<<16)
__device__ __forceinline__ unsigned bpack(float lo, float hi) {
    unsigned a = __float_as_uint(lo);
    unsigned b = __float_as_uint(hi);
    a += 0x7fffu + ((a >> 16) & 1u);
    b += 0x7fffu + ((b >> 16) & 1u);
    return (a >> 16) | (b & 0xffff0000u);
}

// ---------------------------------------------------------------------------
// P1: block (k, h), grid NFP*8 (fast) / NF*8 (fallback), TPB 512.
//   k<40: WW[k][j], UW[k][j] for j in [5h,5h+5); coef_k; Wb slice (if doWb).
//   k>=40: zero-pad Wb row slice.
// ---------------------------------------------------------------------------
__global__ __launch_bounds__(512) void pair_wb_kernel(const float* __restrict__ Wg,
                                                      const float* __restrict__ Ug,
                                                      float* __restrict__ tbl,
                                                      int doWb) {
    const int k = blockIdx.x >> 3;
    const int h = blockIdx.x & 7;
    const int t = threadIdx.x;
    uint2* Wb2 = (uint2*)((unsigned*)(tbl + WB_OFF) + (size_t)k * (D / 2));

    if (k >= NF) {                       // zero-pad rows 40..47 (fast path only)
        Wb2[h * 512 + t] = make_uint2(0u, 0u);
        return;
    }

    const int j0 = h * 5;
    const int wave = t >> 6, lane = t & 63;
    const float4* W4 = (const float4*)Wg;
    const float4* U4 = (const float4*)Ug;

    float ww[5], wu[5], wkk = 0.f, wku = 0.f;
    float4 wkSave;
    #pragma unroll
    for (int j = 0; j < 5; ++j) { ww[j] = 0.f; wu[j] = 0.f; }

    for (int i = 0; i < 8; ++i) {
        const int pos = i * 512 + t;
        float4 wk = W4[(size_t)k * D4 + pos];
        float4 uk = U4[(size_t)k * D4 + pos];
        if (i == h) wkSave = wk;
        wkk += dot4(wk, wk);
        wku += dot4(wk, uk);
        #pragma unroll
        for (int j = 0; j < 5; ++j) {
            float4 wj = W4[(size_t)(j0 + j) * D4 + pos];
            float4 uj = U4[(size_t)(j0 + j) * D4 + pos];
            ww[j] += dot4(wk, wj);
            wu[j] += dot4(wk, uj);
        }
    }

    if (doWb) {
        uint2 p;
        p.x = bpack(wkSave.x, wkSave.y);
        p.y = bpack(wkSave.z, wkSave.w);
        Wb2[h * 512 + t] = p;
    }

    float v[12];
    #pragma unroll
    for (int j = 0; j < 5; ++j) { v[j] = ww[j]; v[5 + j] = wu[j]; }
    v[10] = wkk; v[11] = wku;
    #pragma unroll
    for (int e = 0; e < 12; ++e) {
        #pragma unroll
        for (int off = 32; off >= 1; off >>= 1) v[e] += __shfl_xor(v[e], off);
    }

    __shared__ float red[8][12];
    __shared__ float fin[12];
    if (lane == 0) {
        #pragma unroll
        for (int e = 0; e < 12; ++e) red[wave][e] = v[e];
    }
    __syncthreads();
    if (t < 12) {
        float s = 0.f;
        #pragma unroll
        for (int w = 0; w < 8; ++w) s += red[w][t];
        fin[t] = s;
        if (t < 5)       tbl[WW_OFF + k * NF + j0 + t] = s;
        else if (t < 10) tbl[UW_OFF + k * NF + j0 + (t - 5)] = s;
    }
    __syncthreads();
    if (t == 0 && h == 0) {
        float wwd = fin[10], wud = fin[11];
        float sp = (wud > 0.f) ? (wud + log1pf(expf(-wud))) : log1pf(expf(wud));
        tbl[COEF_OFF + k] = ((-1.f + sp) - wud) / wwd;
    }
}

// ---------------------------------------------------------------------------
// G: MFMA partial GEMM. grid = 128 row-tiles x KSPLIT=8 -> 1024 blocks,
// TPB 256 (4 waves). Unchanged from R7 (proven; dropped out of top-5).
// ---------------------------------------------------------------------------
__global__ __launch_bounds__(256) void gemm_part_kernel(const float* __restrict__ Xg,
                                                        float* __restrict__ tbl) {
    const int t = threadIdx.x, w = t >> 6, l = t & 63;
    const int rt = blockIdx.x >> 3, ks = blockIdx.x & 7;
    const int r = l & 15, kg = l >> 4;

    __shared__ float red[4][16][NFP + 1];

    const unsigned* WbU = (const unsigned*)(tbl + WB_OFF);
    f32x4 acc0 = {0.f, 0.f, 0.f, 0.f};
    f32x4 acc1 = acc0, acc2 = acc0;

    const float*    xrow = Xg + (size_t)(rt * 16 + r) * D + kg * 8;
    const unsigned* b0p = WbU + (size_t)(r)      * (D / 2) + kg * 4;
    const unsigned* b1p = WbU + (size_t)(16 + r) * (D / 2) + kg * 4;
    const unsigned* b2p = WbU + (size_t)(32 + r) * (D / 2) + kg * 4;
    const int kbase = ks * 2048 + w * 512;

    #pragma unroll 4
    for (int kk = 0; kk < 512; kk += 32) {
        const int kb = kbase + kk;
        float4 xa = *(const float4*)(xrow + kb);
        float4 xb = *(const float4*)(xrow + kb + 4);
        FragU af;
        af.u[0] = bpack(xa.x, xa.y); af.u[1] = bpack(xa.z, xa.w);
        af.u[2] = bpack(xb.x, xb.y); af.u[3] = bpack(xb.z, xb.w);
        const int ku = kb >> 1;
        bf16x8 b0 = *(const bf16x8*)(b0p + ku);
        bf16x8 b1 = *(const bf16x8*)(b1p + ku);
        bf16x8 b2 = *(const bf16x8*)(b2p + ku);
        acc0 = __builtin_amdgcn_mfma_f32_16x16x32_bf16(af.b, b0, acc0, 0, 0, 0);
        acc1 = __builtin_amdgcn_mfma_f32_16x16x32_bf16(af.b, b1, acc1, 0, 0, 0);
        acc2 = __builtin_amdgcn_mfma_f32_16x16x32_bf16(af.b, b2, acc2, 0, 0, 0);
    }

    #pragma unroll
    for (int q = 0; q < 4; ++q) {
        red[w][kg * 4 + q][r]      = acc0[q];
        red[w][kg * 4 + q][16 + r] = acc1[q];
        red[w][kg * 4 + q][32 + r] = acc2[q];
    }
    __syncthreads();

    float* c0p = tbl + C0P_OFF;
    for (int e = t; e < 16 * NF; e += 256) {
        const int row = e / NF, fl = e - row * NF;
        float s = red[0][row][fl] + red[1][row][fl] +
                  red[2][row][fl] + red[3][row][fl];
        c0p[((size_t)(rt * 16 + row) * KSPLIT + ks) * NF + fl] = s;
    }
}

// ---------------------------------------------------------------------------
// R: reduce K-split partials + 40-step recurrence -> aT[row][j] (coalesced).
// grid 128, TPB 1024 (one wave per row of the 16-row tile).
// ---------------------------------------------------------------------------
__global__ __launch_bounds__(1024) void reduce_rec_kernel(const float* __restrict__ Bg,
                                                          float* __restrict__ tbl) {
    const int t = threadIdx.x;
    const int wave = t >> 6, lane = t & 63;

    __shared__ float gts[NF][NF + 1];
    __shared__ float bsS[NF];
    for (int e = t; e < NF * NF; e += 1024) {
        const int jj = e % NF;
        gts[e / NF][jj] = tbl[UW_OFF + e] + tbl[COEF_OFF + jj] * tbl[WW_OFF + e];
    }
    if (t < NF) bsS[t] = Bg[t];
    __syncthreads();

    const int g = blockIdx.x * 16 + wave;
    const float* cp = tbl + C0P_OFF + (size_t)g * (KSPLIT * NF);

    float c0 = 0.f;
    if (lane < NF) {
        #pragma unroll
        for (int s = 0; s < KSPLIT; ++s) c0 += cp[s * NF + lane];
        c0 += bsS[lane];
    }

    float aj = 0.f;
    for (int k = 0; k < NF; ++k) {
        float gv = (lane < k) ? gts[k][lane] : 0.f;
        float tv = aj * gv;
        #pragma unroll
        for (int off = 32; off >= 1; off >>= 1) tv += __shfl_xor(tv, off);
        float ck = __shfl(c0, k);
        float ak = tanhf(ck + tv);
        if (lane == k) aj = ak;
    }
    if (lane < NF) tbl[AT_OFF + (size_t)g * NF + lane] = aj;   // [S][NF] coalesced
}

// ---------------------------------------------------------------------------
// U: UH[k] = U[k] + coef_k * W[k] (fp32), written over the dead c0p region.
// grid NF*16 = 640, TPB 256, 1 float4/thread.
// ---------------------------------------------------------------------------
__global__ __launch_bounds__(256) void uh_kernel(const float* __restrict__ Wg,
                                                 const float* __restrict__ Ug,
                                                 float* __restrict__ tbl) {
    const int k = blockIdx.x >> 4;
    const int h = blockIdx.x & 15;
    const float cf = tbl[COEF_OFF + k];
    const int i = h * 256 + threadIdx.x;
    const float4 w = ((const float4*)Wg)[(size_t)k * D4 + i];
    const float4 u = ((const float4*)Ug)[(size_t)k * D4 + i];
    float4 r;
    r.x = fmaf(cf, w.x, u.x); r.y = fmaf(cf, w.y, u.y);
    r.z = fmaf(cf, w.z, u.z); r.w = fmaf(cf, w.w, u.w);
    ((float4*)(tbl + UH_OFF))[(size_t)k * D4 + i] = r;
}

// ---------------------------------------------------------------------------
// C: out[r] = x0[r] + sum_k a[r][k] * uhat_k.  grid 2048 (256 row-blocks x
// 8 col-eighths), TPB 256. a-values staged once in LDS.
// R8 BUG FIXED: staging guard `if (t < NF*8)` with NF*8=320 > 256 threads
// left rows 6-7 of each block with poisoned a-values -> strided loop now.
// ---------------------------------------------------------------------------
__global__ __launch_bounds__(256) void apply_kernel(const float* __restrict__ Xg,
                                                    const float* __restrict__ tbl,
                                                    float* __restrict__ Og) {
    const int bid = blockIdx.x;
    const int rblk = bid >> 3, cq = bid & 7;
    const int t = threadIdx.x;
    const int r0 = rblk * 8;

    __shared__ __align__(16) float aL[NF][8];
    for (int e = t; e < NF * 8; e += 256) {
        const int r = e / NF, k = e - r * NF;       // coalesced [S][NF] read
        aL[k][r] = tbl[AT_OFF + (size_t)(r0 + r) * NF + k];
    }
    __syncthreads();

    const float4* X4  = (const float4*)Xg;
    const float4* UH4 = (const float4*)(tbl + UH_OFF);
    float4* O4 = (float4*)Og;

    #pragma unroll 1
    for (int p = 0; p < 2; ++p) {
        const int col = cq * 512 + p * 256 + t;
        float4 o[8];
        #pragma unroll
        for (int r = 0; r < 8; ++r)
            o[r] = X4[(size_t)(r0 + r) * D4 + col];

        #pragma unroll 4
        for (int k = 0; k < NF; ++k) {
            float4 uh = UH4[(size_t)k * D4 + col];
            float4 alo = *(const float4*)&aL[k][0];
            float4 ahi = *(const float4*)&aL[k][4];
            fma4(o[0], alo.x, uh); fma4(o[1], alo.y, uh);
            fma4(o[2], alo.z, uh); fma4(o[3], alo.w, uh);
            fma4(o[4], ahi.x, uh); fma4(o[5], ahi.y, uh);
            fma4(o[6], ahi.z, uh); fma4(o[7], ahi.w, uh);
        }
        #pragma unroll
        for (int r = 0; r < 8; ++r)
            O4[(size_t)(r0 + r) * D4 + col] = o[r];
    }
}

// ---------------------------------------------------------------------------
// Fallback (ws too small): R5's proven scalar kernel.
// ---------------------------------------------------------------------------
__global__ __launch_bounds__(TPB) void flow_main_fb(const float* __restrict__ Xg,
                                                    const float* __restrict__ Wg,
                                                    const float* __restrict__ Ug,
                                                    const float* __restrict__ Bg,
                                                    const float* __restrict__ tbl,
                                                    float* __restrict__ Og) {
    const int t = threadIdx.x;
    const int wave = t >> 6, lane = t & 63;
    const int rowBase = blockIdx.x * ROWS;

    __shared__ __align__(16) float xs[2][ROWS][CHUNK];
    __shared__ __align__(16) float gts[NF][NF + 1];
    __shared__ __align__(16) float c0p[NF][ROWS];
    __shared__ __align__(16) float aTs[NF][ROWS];
    __shared__ float bsS[NF];
    __shared__ float coefS[NF];

    const float4* X4 = (const float4*)Xg;
    const float4* W4 = (const float4*)Wg;
    const float4* U4 = (const float4*)Ug;

    for (int e = t; e < NF * NF; e += TPB) {
        const int jj = e % NF;
        gts[e / NF][jj] = tbl[UW_OFF + e] + tbl[COEF_OFF + jj] * tbl[WW_OFF + e];
    }
    if (t < NF) { bsS[t] = Bg[t]; coefS[t] = tbl[COEF_OFF + t]; }

    const int srow = (t >> 8) * 2;
    const int sc4  = t & 255;

    float4 p0 = X4[(size_t)(rowBase + srow)     * D4 + sc4];
    float4 p1 = X4[(size_t)(rowBase + srow + 1) * D4 + sc4];
    *(float4*)&xs[0][srow][sc4 * 4]     = p0;
    *(float4*)&xs[0][srow + 1][sc4 * 4] = p1;
    __syncthreads();

    const int kt = wave & 7, rt = wave >> 3;
    const int k0 = kt * 5, r0 = rt * 4;

    float acc[4][5];
    #pragma unroll
    for (int r = 0; r < 4; ++r)
        #pragma unroll
        for (int kk = 0; kk < 5; ++kk) acc[r][kk] = 0.f;

    int b = 0;
    for (int c = 0; c < NCHUNK; ++c) {
        if (c + 1 < NCHUNK) {
            p0 = X4[(size_t)(rowBase + srow)     * D4 + (c + 1) * CH4 + sc4];
            p1 = X4[(size_t)(rowBase + srow + 1) * D4 + (c + 1) * CH4 + sc4];
        }
        #pragma unroll 1
        for (int s = 0; s < 4; ++s) {
            const int col4 = c * CH4 + s * 64 + lane;
            float4 wv[5];
            #pragma unroll
            for (int kk = 0; kk < 5; ++kk)
                wv[kk] = W4[(size_t)(k0 + kk) * D4 + col4];
            const int lc = (s * 64 + lane) * 4;
            #pragma unroll
            for (int r = 0; r < 4; ++r) {
                float4 xv = *(const float4*)&xs[b][r0 + r][lc];
                #pragma unroll
                for (int kk = 0; kk < 5; ++kk)
                    acc[r][kk] = fmaf(xv.x, wv[kk].x,
                                 fmaf(xv.y, wv[kk].y,
                                 fmaf(xv.z, wv[kk].z,
                                 fmaf(xv.w, wv[kk].w, acc[r][kk]))));
            }
        }
        if (c + 1 < NCHUNK) {
            *(float4*)&xs[b ^ 1][srow][sc4 * 4]     = p0;
            *(float4*)&xs[b ^ 1][srow + 1][sc4 * 4] = p1;
        }
        __syncthreads();
        b ^= 1;
    }

    #pragma unroll
    for (int r = 0; r < 4; ++r)
        #pragma unroll
        for (int kk = 0; kk < 5; ++kk) {
            float v = acc[r][kk];
            #pragma unroll
            for (int off = 32; off >= 1; off >>= 1) v += __shfl_xor(v, off);
            acc[r][kk] = v;
        }
    if (lane == 0) {
        #pragma unroll
        for (int kk = 0; kk < 5; ++kk)
            #pragma unroll
            for (int r = 0; r < 4; ++r)
                c0p[k0 + kk][r0 + r] = acc[r][kk];
    }
    __syncthreads();

    float4 o[ROWS];
    {
        const int col = wave * 64 + lane;
        #pragma unroll
        for (int r = 0; r < ROWS; ++r)
            o[r] = X4[(size_t)(rowBase + r) * D4 + col];
    }

    if (wave < ROWS) {
        const int r = wave, j = lane;
        float aj = 0.f;
        for (int k = 0; k < NF; ++k) {
            float gv = (j < k) ? gts[k][j] : 0.f;
            float tv = aj * gv;
            #pragma unroll
            for (int off = 32; off >= 1; off >>= 1) tv += __shfl_xor(tv, off);
            float sum = c0p[k][r] + bsS[k] + tv;
            float ak = tanhf(sum);
            if (j == k) aj = ak;
        }
        if (j < NF) aTs[j][r] = aj;
    }
    __syncthreads();

    float4* O4 = (float4*)Og;
    #pragma unroll 1
    for (int p = 0; p < 4; ++p) {
        const int col = p * 1024 + wave * 64 + lane;
        if (p > 0) {
            #pragma unroll
            for (int r = 0; r < ROWS; ++r)
                o[r] = X4[(size_t)(rowBase + r) * D4 + col];
        }
        #pragma unroll 2
        for (int k = 0; k < NF; ++k) {
            float4 uu = U4[(size_t)k * D4 + col];
            float4 wv = W4[(size_t)k * D4 + col];
            const float cf = coefS[k];
            float4 uh;
            uh.x = fmaf(cf, wv.x, uu.x);
            uh.y = fmaf(cf, wv.y, uu.y);
            uh.z = fmaf(cf, wv.z, uu.z);
            uh.w = fmaf(cf, wv.w, uu.w);
            float4 alo = *(const float4*)&aTs[k][0];
            float4 ahi = *(const float4*)&aTs[k][4];
            fma4(o[0], alo.x, uh); fma4(o[1], alo.y, uh);
            fma4(o[2], alo.z, uh); fma4(o[3], alo.w, uh);
            fma4(o[4], ahi.x, uh); fma4(o[5], ahi.y, uh);
            fma4(o[6], ahi.z, uh); fma4(o[7], ahi.w, uh);
        }
        #pragma unroll
        for (int r = 0; r < ROWS; ++r)
            O4[(size_t)(rowBase + r) * D4 + col] = o[r];
    }
}

extern "C" void kernel_launch(void* const* d_in, const int* in_sizes, int n_in,
                              void* d_out, int out_size, void* d_ws, size_t ws_size,
                              hipStream_t stream) {
    const float* X  = (const float*)d_in[0];
    const float* Wg = (const float*)d_in[1];
    const float* Ug = (const float*)d_in[2];
    const float* Bg = (const float*)d_in[3];
    float* out = (float*)d_out;
    float* tbl = (float*)d_ws;

    const bool fast = ws_size >= (size_t)WS_NEED * sizeof(float);

    if (fast) {
        pair_wb_kernel<<<NFP * 8, 512, 0, stream>>>(Wg, Ug, tbl, 1);
        gemm_part_kernel<<<(S / 16) * KSPLIT, 256, 0, stream>>>(X, tbl);
        reduce_rec_kernel<<<S / 16, 1024, 0, stream>>>(Bg, tbl);
        uh_kernel<<<NF * 16, 256, 0, stream>>>(Wg, Ug, tbl);   // writes over dead c0p
        apply_kernel<<<(S / 8) * 8, 256, 0, stream>>>(X, tbl, out);
    } else {
        pair_wb_kernel<<<NF * 8, 512, 0, stream>>>(Wg, Ug, tbl, 0);
        flow_main_fb<<<S / ROWS, TPB, 0, stream>>>(X, Wg, Ug, Bg, tbl, out);
    }
}

// Round 10
// 125.682 us; speedup vs baseline: 1.4089x; 1.0329x over previous
//
#include <hip/hip_runtime.h>
#include <math.h>

#define D      16384
#define D4     4096    // D/4
#define S      2048
#define NF     40
#define NFP    48      // padded flow count for MFMA (3 x 16)
#define ROWS   8
#define TPB    1024
#define CH4    256
#define CHUNK  1024
#define NCHUNK 16
#define KSPLIT 8       // K-splits in the MFMA GEMM

// ---- d_ws float offsets (fast path), ~7.2 MB total (ws measured 512 MB) ----
#define WW_OFF     0                        // WW[k][j] = w_j . w_k   (1600)
#define UW_OFF     1600                     // UW[k][j] = u_j . w_k   (1600)
#define COEF_OFF   3200                     // coef[j]                (40)
#define AT_OFF     4096                     // aT[S][NF] fp32         (81920)
#define WB_OFF     (AT_OFF + NF * S)        // Wb bf16 [NFP][D] as u32 (NFP*D/2 slots)
#define C0P_OFF    (WB_OFF + (NFP * D) / 2) // c0 partials [S][KSPLIT][NF]  (655360)
#define UH_OFF     (C0P_OFF + S * KSPLIT * NF) // uhat fp32 [NF][D] (dedicated region)
#define WS_NEED    (UH_OFF + NF * D)

typedef __attribute__((ext_vector_type(8))) __bf16 bf16x8;
typedef __attribute__((ext_vector_type(4))) float  f32x4;
union FragU { unsigned u[4]; bf16x8 b; };

__device__ __forceinline__ float dot4(float4 a, float4 b) {
    return fmaf(a.x, b.x, fmaf(a.y, b.y, fmaf(a.z, b.z, a.w * b.w)));
}
__device__ __forceinline__ void fma4(float4& o, float a, float4 u) {
    o.x = fmaf(a, u.x, o.x); o.y = fmaf(a, u.y, o.y);
    o.z = fmaf(a, u.z, o.z); o.w = fmaf(a, u.w, o.w);
}
// fp32 -> bf16 (RNE) pair pack: returns (lo | hi<<16)
__device__ __forceinline__ unsigned bpack(float lo, float hi) {
    unsigned a = __float_as_uint(lo);
    unsigned b = __float_as_uint(hi);
    a += 0x7fffu + ((a >> 16) & 1u);
    b += 0x7fffu + ((b >> 16) & 1u);
    return (a >> 16) | (b & 0xffff0000u);
}

// ---------------------------------------------------------------------------
// P1: block (k, h), grid NFP*8 (fast) / NF*8 (fallback), TPB 512.
//   k<40: WW[k][j], UW[k][j] for j in [5h,5h+5); coef (local reduction);
//         if doWb: Wb bf16 slice h AND UH slice h = u + coef*w — both reuse
//         the i==h W/U loads (zero extra global traffic; R6-proven pattern).
//   k>=40: zero-pad Wb row slice.
// ---------------------------------------------------------------------------
__global__ __launch_bounds__(512) void pair_wb_kernel(const float* __restrict__ Wg,
                                                      const float* __restrict__ Ug,
                                                      float* __restrict__ tbl,
                                                      int doWb) {
    const int k = blockIdx.x >> 3;
    const int h = blockIdx.x & 7;
    const int t = threadIdx.x;
    uint2* Wb2 = (uint2*)((unsigned*)(tbl + WB_OFF) + (size_t)k * (D / 2));

    if (k >= NF) {                       // zero-pad rows 40..47 (fast path only)
        Wb2[h * 512 + t] = make_uint2(0u, 0u);
        return;
    }

    const int j0 = h * 5;
    const int wave = t >> 6, lane = t & 63;
    const float4* W4 = (const float4*)Wg;
    const float4* U4 = (const float4*)Ug;

    float ww[5], wu[5], wkk = 0.f, wku = 0.f;
    float4 wkSave, ukSave;
    #pragma unroll
    for (int j = 0; j < 5; ++j) { ww[j] = 0.f; wu[j] = 0.f; }

    for (int i = 0; i < 8; ++i) {
        const int pos = i * 512 + t;
        float4 wk = W4[(size_t)k * D4 + pos];
        float4 uk = U4[(size_t)k * D4 + pos];
        if (i == h) { wkSave = wk; ukSave = uk; }
        wkk += dot4(wk, wk);
        wku += dot4(wk, uk);
        #pragma unroll
        for (int j = 0; j < 5; ++j) {
            float4 wj = W4[(size_t)(j0 + j) * D4 + pos];
            float4 uj = U4[(size_t)(j0 + j) * D4 + pos];
            ww[j] += dot4(wk, wj);
            wu[j] += dot4(wk, uj);
        }
    }

    if (doWb) {
        uint2 p;
        p.x = bpack(wkSave.x, wkSave.y);
        p.y = bpack(wkSave.z, wkSave.w);
        Wb2[h * 512 + t] = p;
    }

    float v[12];
    #pragma unroll
    for (int j = 0; j < 5; ++j) { v[j] = ww[j]; v[5 + j] = wu[j]; }
    v[10] = wkk; v[11] = wku;
    #pragma unroll
    for (int e = 0; e < 12; ++e) {
        #pragma unroll
        for (int off = 32; off >= 1; off >>= 1) v[e] += __shfl_xor(v[e], off);
    }

    __shared__ float red[8][12];
    __shared__ float fin[12];
    __shared__ float coefL;
    if (lane == 0) {
        #pragma unroll
        for (int e = 0; e < 12; ++e) red[wave][e] = v[e];
    }
    __syncthreads();
    if (t < 12) {
        float s = 0.f;
        #pragma unroll
        for (int w = 0; w < 8; ++w) s += red[w][t];
        fin[t] = s;
        if (t < 5)       tbl[WW_OFF + k * NF + j0 + t] = s;
        else if (t < 10) tbl[UW_OFF + k * NF + j0 + (t - 5)] = s;
    }
    __syncthreads();
    if (t == 0) {
        float wwd = fin[10], wud = fin[11];
        float sp = (wud > 0.f) ? (wud + log1pf(expf(-wud))) : log1pf(expf(wud));
        float cf = ((-1.f + sp) - wud) / wwd;
        coefL = cf;
        if (h == 0) tbl[COEF_OFF + k] = cf;
    }
    __syncthreads();

    if (doWb) {   // UH slice h, from the saved i==h values (R6-proven)
        const float cf = coefL;
        float4 r;
        r.x = fmaf(cf, wkSave.x, ukSave.x);
        r.y = fmaf(cf, wkSave.y, ukSave.y);
        r.z = fmaf(cf, wkSave.z, ukSave.z);
        r.w = fmaf(cf, wkSave.w, ukSave.w);
        ((float4*)(tbl + UH_OFF))[(size_t)k * D4 + h * 512 + t] = r;
    }
}

// ---------------------------------------------------------------------------
// G: MFMA partial GEMM. grid = 128 row-tiles x KSPLIT=8 -> 1024 blocks,
// TPB 256 (4 waves). Unchanged from R7/R9 (proven).
// ---------------------------------------------------------------------------
__global__ __launch_bounds__(256) void gemm_part_kernel(const float* __restrict__ Xg,
                                                        float* __restrict__ tbl) {
    const int t = threadIdx.x, w = t >> 6, l = t & 63;
    const int rt = blockIdx.x >> 3, ks = blockIdx.x & 7;
    const int r = l & 15, kg = l >> 4;

    __shared__ float red[4][16][NFP + 1];

    const unsigned* WbU = (const unsigned*)(tbl + WB_OFF);
    f32x4 acc0 = {0.f, 0.f, 0.f, 0.f};
    f32x4 acc1 = acc0, acc2 = acc0;

    const float*    xrow = Xg + (size_t)(rt * 16 + r) * D + kg * 8;
    const unsigned* b0p = WbU + (size_t)(r)      * (D / 2) + kg * 4;
    const unsigned* b1p = WbU + (size_t)(16 + r) * (D / 2) + kg * 4;
    const unsigned* b2p = WbU + (size_t)(32 + r) * (D / 2) + kg * 4;
    const int kbase = ks * 2048 + w * 512;

    #pragma unroll 4
    for (int kk = 0; kk < 512; kk += 32) {
        const int kb = kbase + kk;
        float4 xa = *(const float4*)(xrow + kb);
        float4 xb = *(const float4*)(xrow + kb + 4);
        FragU af;
        af.u[0] = bpack(xa.x, xa.y); af.u[1] = bpack(xa.z, xa.w);
        af.u[2] = bpack(xb.x, xb.y); af.u[3] = bpack(xb.z, xb.w);
        const int ku = kb >> 1;
        bf16x8 b0 = *(const bf16x8*)(b0p + ku);
        bf16x8 b1 = *(const bf16x8*)(b1p + ku);
        bf16x8 b2 = *(const bf16x8*)(b2p + ku);
        acc0 = __builtin_amdgcn_mfma_f32_16x16x32_bf16(af.b, b0, acc0, 0, 0, 0);
        acc1 = __builtin_amdgcn_mfma_f32_16x16x32_bf16(af.b, b1, acc1, 0, 0, 0);
        acc2 = __builtin_amdgcn_mfma_f32_16x16x32_bf16(af.b, b2, acc2, 0, 0, 0);
    }

    #pragma unroll
    for (int q = 0; q < 4; ++q) {
        red[w][kg * 4 + q][r]      = acc0[q];
        red[w][kg * 4 + q][16 + r] = acc1[q];
        red[w][kg * 4 + q][32 + r] = acc2[q];
    }
    __syncthreads();

    float* c0p = tbl + C0P_OFF;
    for (int e = t; e < 16 * NF; e += 256) {
        const int row = e / NF, fl = e - row * NF;
        float s = red[0][row][fl] + red[1][row][fl] +
                  red[2][row][fl] + red[3][row][fl];
        c0p[((size_t)(rt * 16 + row) * KSPLIT + ks) * NF + fl] = s;
    }
}

// ---------------------------------------------------------------------------
// R: reduce K-split partials + 40-step recurrence -> aT[row][j] (coalesced).
// grid 128, TPB 1024 (one wave per row of the 16-row tile). Unchanged.
// ---------------------------------------------------------------------------
__global__ __launch_bounds__(1024) void reduce_rec_kernel(const float* __restrict__ Bg,
                                                          float* __restrict__ tbl) {
    const int t = threadIdx.x;
    const int wave = t >> 6, lane = t & 63;

    __shared__ float gts[NF][NF + 1];
    __shared__ float bsS[NF];
    for (int e = t; e < NF * NF; e += 1024) {
        const int jj = e % NF;
        gts[e / NF][jj] = tbl[UW_OFF + e] + tbl[COEF_OFF + jj] * tbl[WW_OFF + e];
    }
    if (t < NF) bsS[t] = Bg[t];
    __syncthreads();

    const int g = blockIdx.x * 16 + wave;
    const float* cp = tbl + C0P_OFF + (size_t)g * (KSPLIT * NF);

    float c0 = 0.f;
    if (lane < NF) {
        #pragma unroll
        for (int s = 0; s < KSPLIT; ++s) c0 += cp[s * NF + lane];
        c0 += bsS[lane];
    }

    float aj = 0.f;
    for (int k = 0; k < NF; ++k) {
        float gv = (lane < k) ? gts[k][lane] : 0.f;
        float tv = aj * gv;
        #pragma unroll
        for (int off = 32; off >= 1; off >>= 1) tv += __shfl_xor(tv, off);
        float ck = __shfl(c0, k);
        float ak = tanhf(ck + tv);
        if (lane == k) aj = ak;
    }
    if (lane < NF) tbl[AT_OFF + (size_t)g * NF + lane] = aj;   // [S][NF] coalesced
}

// ---------------------------------------------------------------------------
// C: out[r] = x0[r] + sum_k a[r][k] * uhat_k.  grid 2048 (256 row-blocks x
// 8 col-eighths), TPB 256. a staged in LDS (strided loop — R8 bug fixed in R9).
// NEW: non-temporal out stores — out is write-once; bypassing L2/L3 keeps the
// 128 MB X resident in Infinity Cache from gemm's pass -> X re-read hits L3.
// ---------------------------------------------------------------------------
__global__ __launch_bounds__(256) void apply_kernel(const float* __restrict__ Xg,
                                                    const float* __restrict__ tbl,
                                                    float* __restrict__ Og) {
    const int bid = blockIdx.x;
    const int rblk = bid >> 3, cq = bid & 7;
    const int t = threadIdx.x;
    const int r0 = rblk * 8;

    __shared__ __align__(16) float aL[NF][8];
    for (int e = t; e < NF * 8; e += 256) {
        const int r = e / NF, k = e - r * NF;       // coalesced [S][NF] read
        aL[k][r] = tbl[AT_OFF + (size_t)(r0 + r) * NF + k];
    }
    __syncthreads();

    const float4* X4  = (const float4*)Xg;
    const float4* UH4 = (const float4*)(tbl + UH_OFF);
    f32x4* O4 = (f32x4*)Og;

    #pragma unroll 1
    for (int p = 0; p < 2; ++p) {
        const int col = cq * 512 + p * 256 + t;
        float4 o[8];
        #pragma unroll
        for (int r = 0; r < 8; ++r)
            o[r] = X4[(size_t)(r0 + r) * D4 + col];

        #pragma unroll 4
        for (int k = 0; k < NF; ++k) {
            float4 uh = UH4[(size_t)k * D4 + col];
            float4 alo = *(const float4*)&aL[k][0];
            float4 ahi = *(const float4*)&aL[k][4];
            fma4(o[0], alo.x, uh); fma4(o[1], alo.y, uh);
            fma4(o[2], alo.z, uh); fma4(o[3], alo.w, uh);
            fma4(o[4], ahi.x, uh); fma4(o[5], ahi.y, uh);
            fma4(o[6], ahi.z, uh); fma4(o[7], ahi.w, uh);
        }
        #pragma unroll
        for (int r = 0; r < 8; ++r)
            __builtin_nontemporal_store(*(const f32x4*)&o[r],
                                        &O4[(size_t)(r0 + r) * D4 + col]);
    }
}

// ---------------------------------------------------------------------------
// Fallback (ws too small): R5's proven scalar kernel.
// ---------------------------------------------------------------------------
__global__ __launch_bounds__(TPB) void flow_main_fb(const float* __restrict__ Xg,
                                                    const float* __restrict__ Wg,
                                                    const float* __restrict__ Ug,
                                                    const float* __restrict__ Bg,
                                                    const float* __restrict__ tbl,
                                                    float* __restrict__ Og) {
    const int t = threadIdx.x;
    const int wave = t >> 6, lane = t & 63;
    const int rowBase = blockIdx.x * ROWS;

    __shared__ __align__(16) float xs[2][ROWS][CHUNK];
    __shared__ __align__(16) float gts[NF][NF + 1];
    __shared__ __align__(16) float c0p[NF][ROWS];
    __shared__ __align__(16) float aTs[NF][ROWS];
    __shared__ float bsS[NF];
    __shared__ float coefS[NF];

    const float4* X4 = (const float4*)Xg;
    const float4* W4 = (const float4*)Wg;
    const float4* U4 = (const float4*)Ug;

    for (int e = t; e < NF * NF; e += TPB) {
        const int jj = e % NF;
        gts[e / NF][jj] = tbl[UW_OFF + e] + tbl[COEF_OFF + jj] * tbl[WW_OFF + e];
    }
    if (t < NF) { bsS[t] = Bg[t]; coefS[t] = tbl[COEF_OFF + t]; }

    const int srow = (t >> 8) * 2;
    const int sc4  = t & 255;

    float4 p0 = X4[(size_t)(rowBase + srow)     * D4 + sc4];
    float4 p1 = X4[(size_t)(rowBase + srow + 1) * D4 + sc4];
    *(float4*)&xs[0][srow][sc4 * 4]     = p0;
    *(float4*)&xs[0][srow + 1][sc4 * 4] = p1;
    __syncthreads();

    const int kt = wave & 7, rt = wave >> 3;
    const int k0 = kt * 5, r0 = rt * 4;

    float acc[4][5];
    #pragma unroll
    for (int r = 0; r < 4; ++r)
        #pragma unroll
        for (int kk = 0; kk < 5; ++kk) acc[r][kk] = 0.f;

    int b = 0;
    for (int c = 0; c < NCHUNK; ++c) {
        if (c + 1 < NCHUNK) {
            p0 = X4[(size_t)(rowBase + srow)     * D4 + (c + 1) * CH4 + sc4];
            p1 = X4[(size_t)(rowBase + srow + 1) * D4 + (c + 1) * CH4 + sc4];
        }
        #pragma unroll 1
        for (int s = 0; s < 4; ++s) {
            const int col4 = c * CH4 + s * 64 + lane;
            float4 wv[5];
            #pragma unroll
            for (int kk = 0; kk < 5; ++kk)
                wv[kk] = W4[(size_t)(k0 + kk) * D4 + col4];
            const int lc = (s * 64 + lane) * 4;
            #pragma unroll
            for (int r = 0; r < 4; ++r) {
                float4 xv = *(const float4*)&xs[b][r0 + r][lc];
                #pragma unroll
                for (int kk = 0; kk < 5; ++kk)
                    acc[r][kk] = fmaf(xv.x, wv[kk].x,
                                 fmaf(xv.y, wv[kk].y,
                                 fmaf(xv.z, wv[kk].z,
                                 fmaf(xv.w, wv[kk].w, acc[r][kk]))));
            }
        }
        if (c + 1 < NCHUNK) {
            *(float4*)&xs[b ^ 1][srow][sc4 * 4]     = p0;
            *(float4*)&xs[b ^ 1][srow + 1][sc4 * 4] = p1;
        }
        __syncthreads();
        b ^= 1;
    }

    #pragma unroll
    for (int r = 0; r < 4; ++r)
        #pragma unroll
        for (int kk = 0; kk < 5; ++kk) {
            float v = acc[r][kk];
            #pragma unroll
            for (int off = 32; off >= 1; off >>= 1) v += __shfl_xor(v, off);
            acc[r][kk] = v;
        }
    if (lane == 0) {
        #pragma unroll
        for (int kk = 0; kk < 5; ++kk)
            #pragma unroll
            for (int r = 0; r < 4; ++r)
                c0p[k0 + kk][r0 + r] = acc[r][kk];
    }
    __syncthreads();

    float4 o[ROWS];
    {
        const int col = wave * 64 + lane;
        #pragma unroll
        for (int r = 0; r < ROWS; ++r)
            o[r] = X4[(size_t)(rowBase + r) * D4 + col];
    }

    if (wave < ROWS) {
        const int r = wave, j = lane;
        float aj = 0.f;
        for (int k = 0; k < NF; ++k) {
            float gv = (j < k) ? gts[k][j] : 0.f;
            float tv = aj * gv;
            #pragma unroll
            for (int off = 32; off >= 1; off >>= 1) tv += __shfl_xor(tv, off);
            float sum = c0p[k][r] + bsS[k] + tv;
            float ak = tanhf(sum);
            if (j == k) aj = ak;
        }
        if (j < NF) aTs[j][r] = aj;
    }
    __syncthreads();

    float4* O4 = (float4*)Og;
    #pragma unroll 1
    for (int p = 0; p < 4; ++p) {
        const int col = p * 1024 + wave * 64 + lane;
        if (p > 0) {
            #pragma unroll
            for (int r = 0; r < ROWS; ++r)
                o[r] = X4[(size_t)(rowBase + r) * D4 + col];
        }
        #pragma unroll 2
        for (int k = 0; k < NF; ++k) {
            float4 uu = U4[(size_t)k * D4 + col];
            float4 wv = W4[(size_t)k * D4 + col];
            const float cf = coefS[k];
            float4 uh;
            uh.x = fmaf(cf, wv.x, uu.x);
            uh.y = fmaf(cf, wv.y, uu.y);
            uh.z = fmaf(cf, wv.z, uu.z);
            uh.w = fmaf(cf, wv.w, uu.w);
            float4 alo = *(const float4*)&aTs[k][0];
            float4 ahi = *(const float4*)&aTs[k][4];
            fma4(o[0], alo.x, uh); fma4(o[1], alo.y, uh);
            fma4(o[2], alo.z, uh); fma4(o[3], alo.w, uh);
            fma4(o[4], ahi.x, uh); fma4(o[5], ahi.y, uh);
            fma4(o[6], ahi.z, uh); fma4(o[7], ahi.w, uh);
        }
        #pragma unroll
        for (int r = 0; r < ROWS; ++r)
            O4[(size_t)(rowBase + r) * D4 + col] = o[r];
    }
}

extern "C" void kernel_launch(void* const* d_in, const int* in_sizes, int n_in,
                              void* d_out, int out_size, void* d_ws, size_t ws_size,
                              hipStream_t stream) {
    const float* X  = (const float*)d_in[0];
    const float* Wg = (const float*)d_in[1];
    const float* Ug = (const float*)d_in[2];
    const float* Bg = (const float*)d_in[3];
    float* out = (float*)d_out;
    float* tbl = (float*)d_ws;

    const bool fast = ws_size >= (size_t)WS_NEED * sizeof(float);

    if (fast) {
        pair_wb_kernel<<<NFP * 8, 512, 0, stream>>>(Wg, Ug, tbl, 1);
        gemm_part_kernel<<<(S / 16) * KSPLIT, 256, 0, stream>>>(X, tbl);
        reduce_rec_kernel<<<S / 16, 1024, 0, stream>>>(Bg, tbl);
        apply_kernel<<<(S / 8) * 8, 256, 0, stream>>>(X, tbl, out);
    } else {
        pair_wb_kernel<<<NF * 8, 512, 0, stream>>>(Wg, Ug, tbl, 0);
        flow_main_fb<<<S / ROWS, TPB, 0, stream>>>(X, Wg, Ug, Bg, tbl, out);
    }
}